// Round 10
// baseline (252.723 us; speedup 1.0000x reference)
//
#include <hip/hip_runtime.h>
#include <hip/hip_bf16.h>

#define D_MODEL 1024
#define NH 16
#define HD 64
#define BATCH 2
#define SEQ 2048
#define M_TOTAL (BATCH*SEQ)   // 4096

typedef _Float16 f16;
typedef _Float16 half8 __attribute__((ext_vector_type(8)));
typedef _Float16 half4v __attribute__((ext_vector_type(4)));
typedef float floatx4 __attribute__((ext_vector_type(4)));

#if __has_builtin(__builtin_amdgcn_exp2f)
#define EXP2(x) __builtin_amdgcn_exp2f(x)
#else
#define EXP2(x) __expf(0.6931471805599453f * (x))
#endif

__device__ inline void gload_lds16(const void* g, void* l) {
    __builtin_amdgcn_global_load_lds(
        (const __attribute__((address_space(1))) unsigned int*)g,
        (__attribute__((address_space(3))) unsigned int*)l, 16, 0, 0);
}

// ---------------- fused prep: x cast + weight transposes (+ optional E build) ----------
__device__ void trans_body(const float* __restrict__ src, f16* __restrict__ dst,
                           int R, int C, int bx, int by) {
    __shared__ float tile[32][33];
    int tx = threadIdx.x & 31;
    int ty = threadIdx.x >> 5;        // 0..7
    int c0 = bx * 32;
    int r0 = by * 32;
    for (int yy = 0; yy < 32; yy += 8)
        tile[ty + yy][tx] = src[(long)(r0 + ty + yy) * C + c0 + tx];
    __syncthreads();
    for (int yy = 0; yy < 32; yy += 8)
        dst[(long)(c0 + ty + yy) * R + r0 + tx] = (f16)tile[tx][ty + yy];
}

__global__ __launch_bounds__(256) void prep(
    const float* __restrict__ x, f16* __restrict__ xh,
    const float* __restrict__ Wqkv, f16* __restrict__ WqkvT,
    const float* __restrict__ Wout, f16* __restrict__ WoutT,
    const float* __restrict__ mask, f16* __restrict__ E)
{
    int bid = blockIdx.x;
    if (bid < 1024) {
        // x cast: 1,048,576 float4s, grid-stride x4
        int i = bid * 256 + threadIdx.x;
        #pragma unroll
        for (int it = 0; it < 4; ++it, i += 262144) {
            float4 v = ((const float4*)x)[i];
            half4v o = { (f16)v.x, (f16)v.y, (f16)v.z, (f16)v.w };
            *(half4v*)(xh + (long)i * 4) = o;
        }
    } else if (bid < 1024 + 3072) {
        int t = bid - 1024;                    // Wqkv [1024][3072] -> WqkvT
        trans_body(Wqkv, WqkvT, 1024, 3072, t % 96, t / 96);
    } else if (bid < 5120) {
        int t = bid - 4096;                    // Wout [1024][1024] -> WoutT
        trans_body(Wout, WoutT, 1024, 1024, t % 32, t / 32);
    } else {
        // E = mask * log2(e), only launched when E has its own buffer
        int i = (bid - 5120) * 256 + threadIdx.x;
        float4 v = ((const float4*)mask)[i];
        const float L2E = 1.44269504f;
        half4v o = { (f16)(v.x * L2E), (f16)(v.y * L2E), (f16)(v.z * L2E), (f16)(v.w * L2E) };
        *(half4v*)(E + (long)i * 4) = o;
    }
}

// ---------------- m2 = mask * log2(e) standalone (fallback when E overlays xh) --------
__global__ void l2scale_cvt(const float* __restrict__ src, f16* __restrict__ dst, int n4) {
    int i = blockIdx.x * blockDim.x + threadIdx.x;
    if (i < n4) {
        float4 v = ((const float4*)src)[i];
        const float L2E = 1.44269504f;
        half4v o = { (f16)(v.x * L2E), (f16)(v.y * L2E), (f16)(v.z * L2E), (f16)(v.w * L2E) };
        *(half4v*)(dst + (long)i * 4) = o;
    }
}

// ---------------- 128xTN-tile fp16 MFMA GEMM, BK=32 double-buffered ----------------
// LDS stays 32 KB (3 blocks/CU preserved, the R3-dbuf failure mode avoided); one
// barrier per K-step; next tile's global_load_lds issued BEFORE computing current
// tile so load latency hides under MFMA+ds_read. Rows are 32 f16 = 4 chunks of 16B;
// LDS chunk p of row r holds global chunk p ^ (r&3); frag read chunk = quad ^ (l16&3).
// MODE 0 (TN=128): scatter -> Qh [bh][s][d] (x0.125*log2e), Kh [bh][s][d], Vtg [bh][d][s]
// MODE 1 (TN=64):  out[m][n] = acc + bias (fp32)
template<int MODE, int TN>
__global__ __launch_bounds__(256) void gemm_mfma(
    const f16* __restrict__ A, const f16* __restrict__ BT,
    const float* __restrict__ bias,
    f16* __restrict__ Qh, f16* __restrict__ Kh, f16* __restrict__ Vtg,
    float* __restrict__ out, int Kdim)
{
    constexpr int NF = TN / 32;          // n-frags per wave
    __shared__ f16 Ah[2][128 * 32];
    __shared__ f16 Bh[2][TN * 32];
    int tid  = threadIdx.x;
    int wid  = tid >> 6;
    int lane = tid & 63;
    int quad = lane >> 4;
    int l16  = lane & 15;
    int m0 = blockIdx.y * 128;
    int n0 = blockIdx.x * TN;
    int mrow = (wid >> 1) * 64;
    int ncol = (wid & 1) * (TN / 2);
    // staging: lane -> row (lane>>2) within 16-row group, global chunk (lane&3)^(row&3)
    int srow = lane >> 2;                 // 0..15
    int gchunk = (lane & 3) ^ (srow & 3);
    // frag-read swizzled chunk offset (f16 units), lane-constant
    int sw = (quad ^ (l16 & 3)) * 8;

    floatx4 acc[4][NF];
    #pragma unroll
    for (int mb = 0; mb < 4; mb++)
        #pragma unroll
        for (int nb = 0; nb < NF; nb++) acc[mb][nb] = (floatx4){0.f, 0.f, 0.f, 0.f};

    const f16* Abase = A + (long)m0 * Kdim;
    const f16* Bbase = BT + (long)n0 * Kdim;

    auto stage = [&](int buf, int k0) {
        #pragma unroll
        for (int j = 0; j < 2; j++) {
            int r = wid * 32 + j * 16 + srow;
            gload_lds16(Abase + (long)r * Kdim + k0 + gchunk * 8, &Ah[buf][(wid * 32 + j * 16) * 32]);
        }
        if (TN == 128) {
            #pragma unroll
            for (int j = 0; j < 2; j++) {
                int r = wid * 32 + j * 16 + srow;
                gload_lds16(Bbase + (long)r * Kdim + k0 + gchunk * 8, &Bh[buf][(wid * 32 + j * 16) * 32]);
            }
        } else {
            int r = wid * 16 + srow;
            gload_lds16(Bbase + (long)r * Kdim + k0 + gchunk * 8, &Bh[buf][(wid * 16) * 32]);
        }
    };

    stage(0, 0);
    __syncthreads();                      // vmcnt(0) drain: buf0 ready
    int cur = 0;
    for (int k0 = 0; k0 < Kdim; k0 += 32) {
        if (k0 + 32 < Kdim) stage(cur ^ 1, k0 + 32);   // DMA flies under compute
        half8 af[4];
        #pragma unroll
        for (int mb = 0; mb < 4; mb++)
            af[mb] = *(const half8*)&Ah[cur][(mrow + mb * 16 + l16) * 32 + sw];
        #pragma unroll
        for (int nb = 0; nb < NF; nb++) {
            half8 bf = *(const half8*)&Bh[cur][(ncol + nb * 16 + l16) * 32 + sw];
            #pragma unroll
            for (int mb = 0; mb < 4; mb++)
                acc[mb][nb] = __builtin_amdgcn_mfma_f32_16x16x32_f16(af[mb], bf, acc[mb][nb], 0, 0, 0);
        }
        __syncthreads();                  // drains stage(cur^1); all reads of cur done
        cur ^= 1;
    }

    #pragma unroll
    for (int nb = 0; nb < NF; nb++) {
        int n = n0 + ncol + nb * 16 + l16;
        float bv = bias[n];
        int head = 0, t = 0, d = 0;
        if (MODE == 0) { head = n / 192; int rem = n % 192; t = rem / 64; d = rem % 64; }
        #pragma unroll
        for (int mb = 0; mb < 4; mb++) {
            int mbase = m0 + mrow + mb * 16 + quad * 4;
            if (MODE == 0) {
                int b = mbase >> 11;
                int s = mbase & 2047;
                long bh = b * NH + head;
                if (t == 2) {
                    half4v pack;
                    #pragma unroll
                    for (int r = 0; r < 4; r++) pack[r] = (f16)(acc[mb][nb][r] + bv);
                    *(half4v*)&Vtg[(bh * HD + d) * SEQ + s] = pack;
                } else if (t == 0) {
                    // 0.125 (1/sqrt(64)) * log2(e): QK^T lands directly in log2 domain
                    #pragma unroll
                    for (int r = 0; r < 4; r++)
                        Qh[(bh * SEQ + s + r) * HD + d] = (f16)((acc[mb][nb][r] + bv) * 0.18033688f);
                } else {
                    #pragma unroll
                    for (int r = 0; r < 4; r++)
                        Kh[(bh * SEQ + s + r) * HD + d] = (f16)(acc[mb][nb][r] + bv);
                }
            } else {
                #pragma unroll
                for (int r = 0; r < 4; r++)
                    out[(long)(mbase + r) * D_MODEL + n] = acc[mb][nb][r] + bv;
            }
        }
    }
}

// ---------------- flash attention v9: R7 structure, launch_bounds cap REMOVED ---------
// grid (16, 32) = 512 blocks, 512 threads = 8 waves. Wave (qg = wid&3, kg = wid>>2)
// owns 32 q-rows and every other k-tile. Block stages 4 tiles/iter (K/V for two
// consecutive k-steps); each wave reads only its kg's tiles -> per-CU K/V frag-read
// traffic HALVED vs 16q/wave, at 16 waves/CU (2 blocks x 8 waves; LDS 67.5 KB).
// R7 proved correctness; its 176us was the __launch_bounds__(512,4) VGPR-64 spill
// (525 MB scratch traffic). Natural allocation (~116 VGPR, cf. R6) fits 4 waves/SIMD.
__global__ __launch_bounds__(512) void attn(
    const f16* __restrict__ Qh, const f16* __restrict__ Kh, const f16* __restrict__ Vtg,
    const f16* __restrict__ E, f16* __restrict__ valh)
{
    extern __shared__ f16 sm[];
    f16* Kt0 = sm;            // [64*64] keys (2t)*64
    f16* Kt1 = sm + 4096;     // keys (2t+1)*64
    f16* Vt0 = sm + 8192;
    f16* Vt1 = sm + 12288;
    f16* Plb = sm + 16384;    // [8][32*68]
    int tid  = threadIdx.x;
    int wid  = tid >> 6;             // 0..7
    int lane = tid & 63;
    int quad = lane >> 4;
    int l16  = lane & 15;
    int qg = wid & 3;
    int kg = wid >> 2;

    int id   = blockIdx.y * 16 + blockIdx.x;   // linear dispatch id
    int xcd  = id & 7;
    int slot = id >> 3;
    int bh   = ((xcd & 3) << 3) | (slot >> 3);
    int qx   = ((xcd >> 2) << 3) | (slot & 7);
    int b  = bh >> 4;
    int h  = bh & 15;
    int qblk = qx * 128;
    int q0 = qblk + qg * 32;

    int grow = lane >> 3;                     // 0..7
    int gchunk = (lane & 7) ^ (grow & 7);
    int sw0 = ((quad)     ^ (l16 & 7)) * 8;   // k-half 0
    int sw1 = ((quad + 4) ^ (l16 & 7)) * 8;   // k-half 1

    const f16* Qbase = Qh + ((long)bh * SEQ + q0) * HD;
    half8 qf[2][2];
    #pragma unroll
    for (int m = 0; m < 2; m++)
        #pragma unroll
        for (int c = 0; c < 2; c++)
            qf[m][c] = *(const half8*)&Qbase[(long)(m * 16 + l16) * HD + c * 32 + quad * 8];

    half8 onesv;
    #pragma unroll
    for (int j = 0; j < 8; j++) onesv[j] = (f16)1.0f;

    floatx4 Of[2][4];
    floatx4 ssum[2];
    #pragma unroll
    for (int m = 0; m < 2; m++) {
        ssum[m] = (floatx4){0.f, 0.f, 0.f, 0.f};
        #pragma unroll
        for (int nb = 0; nb < 4; nb++) Of[m][nb] = (floatx4){0.f, 0.f, 0.f, 0.f};
    }

    const f16* Kb = Kh + (long)bh * SEQ * HD;
    const f16* Vb = Vtg + (long)bh * HD * SEQ;
    const f16* Eb = E + (long)qblk * SEQ;

    // staging: wave w covers tile (w>>1), rows (w&1)*32..+31 (4 gload calls of 8 rows)
    int stile = wid >> 1;            // 0: K-even, 1: K-odd, 2: V-even, 3: V-odd
    f16* sdst = (stile == 0) ? Kt0 : (stile == 1) ? Kt1 : (stile == 2) ? Vt0 : Vt1;
    bool sK = (stile < 2);
    int skodd = stile & 1;

    f16* Kt = kg ? Kt1 : Kt0;
    f16* Vt = kg ? Vt1 : Vt0;
    f16* Pl = Plb + wid * (32 * 68);

    for (int t = 0; t < 16; ++t) {
        if (t) __syncthreads();      // prior compute's tile reads done
        {
            int kk = (2 * t + skodd) * 64;
            #pragma unroll
            for (int j = 0; j < 4; j++) {
                int r = (wid & 1) * 32 + j * 8 + grow;
                const f16* src = sK ? (Kb + (long)(kk + r) * HD + gchunk * 8)
                                    : (Vb + (long)r * SEQ + kk + gchunk * 8);
                gload_lds16(src, &sdst[((wid & 1) * 32 + j * 8) * 64]);
            }
        }
        __syncthreads();             // vmcnt(0) drain: all 4 tiles visible

        int k0 = (2 * t + kg) * 64;

        // m2 loads: issue before QK so L2 latency hides under MFMAs
        f16 ef[2][4][4];
        #pragma unroll
        for (int m = 0; m < 2; m++)
            #pragma unroll
            for (int r = 0; r < 4; r++) {
                const f16* Erow = Eb + (long)(qg * 32 + m * 16 + quad * 4 + r) * SEQ + k0 + l16;
                #pragma unroll
                for (int kb = 0; kb < 4; kb++) ef[m][r][kb] = Erow[kb * 16];
            }

        // QK^T: 32 q-rows x 64 keys (result already in log2 domain)
        floatx4 sc[2][4];
        __builtin_amdgcn_s_setprio(1);
        #pragma unroll
        for (int kb = 0; kb < 4; kb++) {
            half8 kf0 = *(const half8*)&Kt[(kb * 16 + l16) * 64 + sw0];
            half8 kf1 = *(const half8*)&Kt[(kb * 16 + l16) * 64 + sw1];
            #pragma unroll
            for (int m = 0; m < 2; m++) {
                floatx4 sacc = (floatx4){0.f, 0.f, 0.f, 0.f};
                sacc = __builtin_amdgcn_mfma_f32_16x16x32_f16(qf[m][0], kf0, sacc, 0, 0, 0);
                sacc = __builtin_amdgcn_mfma_f32_16x16x32_f16(qf[m][1], kf1, sacc, 0, 0, 0);
                sc[m][kb] = sacc;
            }
        }
        __builtin_amdgcn_s_setprio(0);

        // p = exp2(s + m2)
        #pragma unroll
        for (int m = 0; m < 2; m++)
            #pragma unroll
            for (int kb = 0; kb < 4; kb++)
                #pragma unroll
                for (int r = 0; r < 4; r++) {
                    float p = EXP2(sc[m][kb][r] + (float)ef[m][r][kb]);
                    Pl[(m * 16 + quad * 4 + r) * 68 + kb * 16 + l16] = (f16)p;
                }

        // wave-private LDS round-trip (C-layout -> A-layout); no barrier needed
        half8 pf[2][2];
        #pragma unroll
        for (int m = 0; m < 2; m++)
            #pragma unroll
            for (int c = 0; c < 2; c++)
                pf[m][c] = *(const half8*)&Pl[(m * 16 + l16) * 68 + c * 32 + quad * 8];

        __builtin_amdgcn_s_setprio(1);
        // denominators: sums[q] += sum_key P[q][key] via ones-B MFMA
        #pragma unroll
        for (int m = 0; m < 2; m++) {
            ssum[m] = __builtin_amdgcn_mfma_f32_16x16x32_f16(pf[m][0], onesv, ssum[m], 0, 0, 0);
            ssum[m] = __builtin_amdgcn_mfma_f32_16x16x32_f16(pf[m][1], onesv, ssum[m], 0, 0, 0);
        }
        #pragma unroll
        for (int nb = 0; nb < 4; nb++) {
            half8 vf0 = *(const half8*)&Vt[(nb * 16 + l16) * 64 + sw0];
            half8 vf1 = *(const half8*)&Vt[(nb * 16 + l16) * 64 + sw1];
            #pragma unroll
            for (int m = 0; m < 2; m++) {
                Of[m][nb] = __builtin_amdgcn_mfma_f32_16x16x32_f16(pf[m][0], vf0, Of[m][nb], 0, 0, 0);
                Of[m][nb] = __builtin_amdgcn_mfma_f32_16x16x32_f16(pf[m][1], vf1, Of[m][nb], 0, 0, 0);
            }
        }
        __builtin_amdgcn_s_setprio(0);
    }

    // ---- cross-kg combine (through LDS, reusing tile+Pl space) ----
    __syncthreads();
    float* xch = (float*)sm;                 // 48 f32/lane stride, 16B-aligned slots
    float* p = xch + (long)(qg * 64 + lane) * 48;
    if (kg == 1) {
        #pragma unroll
        for (int m = 0; m < 2; m++)
            #pragma unroll
            for (int nb = 0; nb < 4; nb++)
                *(floatx4*)(p + (m * 4 + nb) * 4) = Of[m][nb];
        *(floatx4*)(p + 32) = ssum[0];
        *(floatx4*)(p + 40) = ssum[1];
    }
    __syncthreads();
    if (kg == 0) {
        #pragma unroll
        for (int m = 0; m < 2; m++) {
            #pragma unroll
            for (int nb = 0; nb < 4; nb++)
                Of[m][nb] += *(const floatx4*)(p + (m * 4 + nb) * 4);
            ssum[m] += *(const floatx4*)(p + 32 + m * 8);
        }
        float rinv[2][4];
        #pragma unroll
        for (int m = 0; m < 2; m++)
            #pragma unroll
            for (int r = 0; r < 4; r++) rinv[m][r] = 1.f / ssum[m][r];

        #pragma unroll
        for (int m = 0; m < 2; m++)
            #pragma unroll
            for (int nb = 0; nb < 4; nb++)
                #pragma unroll
                for (int r = 0; r < 4; r++) {
                    int q = q0 + m * 16 + quad * 4 + r;
                    int d = nb * 16 + l16;
                    valh[((long)(b * SEQ + q)) * D_MODEL + h * HD + d] = (f16)(Of[m][nb][r] * rinv[m][r]);
                }
    }
}

extern "C" void kernel_launch(void* const* d_in, const int* in_sizes, int n_in,
                              void* d_out, int out_size, void* d_ws, size_t ws_size,
                              hipStream_t stream) {
    const float* x    = (const float*)d_in[0];
    const float* mask = (const float*)d_in[1];
    const float* Wqkv = (const float*)d_in[2];
    const float* bqkv = (const float*)d_in[3];
    const float* Wout = (const float*)d_in[4];
    const float* bout = (const float*)d_in[5];
    float* out = (float*)d_out;

    char* ws = (char*)d_ws;
    f16* xh    = (f16*)(ws + 0);          // 8 MB: [4096][1024]; dead after gemm0
    f16* WqkvT = (f16*)(ws + 8388608);    // 6 MB: [3072][1024]
    f16* WoutT = (f16*)(ws + 14680064);   // 2 MB: [1024][1024]
    f16* Qh    = (f16*)(ws + 16777216);   // 8 MB: [32][2048][64] (pre-scaled 0.125*log2e)
    f16* Kh    = (f16*)(ws + 25165824);   // 8 MB: [32][2048][64]
    f16* Vtg   = (f16*)(ws + 33554432);   // 8 MB: [32][64][2048] (V transposed)
    f16* valh  = (f16*)(ws + 41943040);   // 8 MB: [4096][1024]

    bool sepE = (ws_size >= 58720256);
    f16* E = sepE ? (f16*)(ws + 50331648)   // own 8 MB buffer -> E built inside prep
                  : (f16*)(ws + 0);         // fallback: overlays xh, built after gemm0

    if (sepE) {
        prep<<<9216, 256, 0, stream>>>(x, xh, Wqkv, WqkvT, Wout, WoutT, mask, E);
        gemm_mfma<0, 128><<<dim3(24, 32), 256, 0, stream>>>(xh, WqkvT, bqkv, Qh, Kh, Vtg, nullptr, 1024);
    } else {
        prep<<<5120, 256, 0, stream>>>(x, xh, Wqkv, WqkvT, Wout, WoutT, mask, E);
        gemm_mfma<0, 128><<<dim3(24, 32), 256, 0, stream>>>(xh, WqkvT, bqkv, Qh, Kh, Vtg, nullptr, 1024);
        l2scale_cvt<<<4096, 256, 0, stream>>>(mask, E, SEQ * SEQ / 4);   // xh dead now
    }
    attn<<<dim3(16, 32), 512, 67584, stream>>>(Qh, Kh, Vtg, E, valh);
    gemm_mfma<1, 64><<<dim3(16, 32), 256, 0, stream>>>(valh, WoutT, bout, nullptr, nullptr, nullptr, out, 1024);
}

// Round 11
// 227.131 us; speedup vs baseline: 1.1127x; 1.1127x over previous
//
#include <hip/hip_runtime.h>
#include <hip/hip_bf16.h>

#define D_MODEL 1024
#define NH 16
#define HD 64
#define BATCH 2
#define SEQ 2048
#define M_TOTAL (BATCH*SEQ)   // 4096

typedef _Float16 f16;
typedef _Float16 half8 __attribute__((ext_vector_type(8)));
typedef _Float16 half4v __attribute__((ext_vector_type(4)));
typedef float floatx4 __attribute__((ext_vector_type(4)));

#if __has_builtin(__builtin_amdgcn_exp2f)
#define EXP2(x) __builtin_amdgcn_exp2f(x)
#else
#define EXP2(x) __expf(0.6931471805599453f * (x))
#endif

__device__ inline void gload_lds16(const void* g, void* l) {
    __builtin_amdgcn_global_load_lds(
        (const __attribute__((address_space(1))) unsigned int*)g,
        (__attribute__((address_space(3))) unsigned int*)l, 16, 0, 0);
}

// ---------------- fused prep: x cast + weight transposes (+ optional E build) ----------
__device__ void trans_body(const float* __restrict__ src, f16* __restrict__ dst,
                           int R, int C, int bx, int by) {
    __shared__ float tile[32][33];
    int tx = threadIdx.x & 31;
    int ty = threadIdx.x >> 5;        // 0..7
    int c0 = bx * 32;
    int r0 = by * 32;
    for (int yy = 0; yy < 32; yy += 8)
        tile[ty + yy][tx] = src[(long)(r0 + ty + yy) * C + c0 + tx];
    __syncthreads();
    for (int yy = 0; yy < 32; yy += 8)
        dst[(long)(c0 + ty + yy) * R + r0 + tx] = (f16)tile[tx][ty + yy];
}

__global__ __launch_bounds__(256) void prep(
    const float* __restrict__ x, f16* __restrict__ xh,
    const float* __restrict__ Wqkv, f16* __restrict__ WqkvT,
    const float* __restrict__ Wout, f16* __restrict__ WoutT,
    const float* __restrict__ mask, f16* __restrict__ E)
{
    int bid = blockIdx.x;
    if (bid < 1024) {
        // x cast: 1,048,576 float4s, grid-stride x4
        int i = bid * 256 + threadIdx.x;
        #pragma unroll
        for (int it = 0; it < 4; ++it, i += 262144) {
            float4 v = ((const float4*)x)[i];
            half4v o = { (f16)v.x, (f16)v.y, (f16)v.z, (f16)v.w };
            *(half4v*)(xh + (long)i * 4) = o;
        }
    } else if (bid < 1024 + 3072) {
        int t = bid - 1024;                    // Wqkv [1024][3072] -> WqkvT
        trans_body(Wqkv, WqkvT, 1024, 3072, t % 96, t / 96);
    } else if (bid < 5120) {
        int t = bid - 4096;                    // Wout [1024][1024] -> WoutT
        trans_body(Wout, WoutT, 1024, 1024, t % 32, t / 32);
    } else {
        // E = mask * log2(e), only launched when E has its own buffer
        int i = (bid - 5120) * 256 + threadIdx.x;
        float4 v = ((const float4*)mask)[i];
        const float L2E = 1.44269504f;
        half4v o = { (f16)(v.x * L2E), (f16)(v.y * L2E), (f16)(v.z * L2E), (f16)(v.w * L2E) };
        *(half4v*)(E + (long)i * 4) = o;
    }
}

// ---------------- m2 = mask * log2(e) standalone (fallback when E overlays xh) --------
__global__ void l2scale_cvt(const float* __restrict__ src, f16* __restrict__ dst, int n4) {
    int i = blockIdx.x * blockDim.x + threadIdx.x;
    if (i < n4) {
        float4 v = ((const float4*)src)[i];
        const float L2E = 1.44269504f;
        half4v o = { (f16)(v.x * L2E), (f16)(v.y * L2E), (f16)(v.z * L2E), (f16)(v.w * L2E) };
        *(half4v*)(dst + (long)i * 4) = o;
    }
}

// ---------------- 128xTN-tile fp16 MFMA GEMM, BK=32 double-buffered ----------------
// LDS 32 KB (3 blocks/CU); one barrier per K-step; next tile's DMA issued before
// compute. Rows = 32 f16 = 4 chunks of 16B; chunk p of row r holds global chunk
// p ^ (r&3); frag read chunk = quad ^ (l16&3).
// MODE 0 (TN=128): scatter -> Qh [bh][s][d] (x0.125*log2e), Kh [bh][s][d], Vtg [bh][d][s]
// MODE 1 (TN=64):  out[m][n] = acc + bias (fp32)
template<int MODE, int TN>
__global__ __launch_bounds__(256) void gemm_mfma(
    const f16* __restrict__ A, const f16* __restrict__ BT,
    const float* __restrict__ bias,
    f16* __restrict__ Qh, f16* __restrict__ Kh, f16* __restrict__ Vtg,
    float* __restrict__ out, int Kdim)
{
    constexpr int NF = TN / 32;          // n-frags per wave
    __shared__ f16 Ah[2][128 * 32];
    __shared__ f16 Bh[2][TN * 32];
    int tid  = threadIdx.x;
    int wid  = tid >> 6;
    int lane = tid & 63;
    int quad = lane >> 4;
    int l16  = lane & 15;
    int m0 = blockIdx.y * 128;
    int n0 = blockIdx.x * TN;
    int mrow = (wid >> 1) * 64;
    int ncol = (wid & 1) * (TN / 2);
    int srow = lane >> 2;                 // 0..15
    int gchunk = (lane & 3) ^ (srow & 3);
    int sw = (quad ^ (l16 & 3)) * 8;

    floatx4 acc[4][NF];
    #pragma unroll
    for (int mb = 0; mb < 4; mb++)
        #pragma unroll
        for (int nb = 0; nb < NF; nb++) acc[mb][nb] = (floatx4){0.f, 0.f, 0.f, 0.f};

    const f16* Abase = A + (long)m0 * Kdim;
    const f16* Bbase = BT + (long)n0 * Kdim;

    auto stage = [&](int buf, int k0) {
        #pragma unroll
        for (int j = 0; j < 2; j++) {
            int r = wid * 32 + j * 16 + srow;
            gload_lds16(Abase + (long)r * Kdim + k0 + gchunk * 8, &Ah[buf][(wid * 32 + j * 16) * 32]);
        }
        if (TN == 128) {
            #pragma unroll
            for (int j = 0; j < 2; j++) {
                int r = wid * 32 + j * 16 + srow;
                gload_lds16(Bbase + (long)r * Kdim + k0 + gchunk * 8, &Bh[buf][(wid * 32 + j * 16) * 32]);
            }
        } else {
            int r = wid * 16 + srow;
            gload_lds16(Bbase + (long)r * Kdim + k0 + gchunk * 8, &Bh[buf][(wid * 16) * 32]);
        }
    };

    stage(0, 0);
    __syncthreads();                      // vmcnt(0) drain: buf0 ready
    int cur = 0;
    for (int k0 = 0; k0 < Kdim; k0 += 32) {
        if (k0 + 32 < Kdim) stage(cur ^ 1, k0 + 32);   // DMA flies under compute
        half8 af[4];
        #pragma unroll
        for (int mb = 0; mb < 4; mb++)
            af[mb] = *(const half8*)&Ah[cur][(mrow + mb * 16 + l16) * 32 + sw];
        #pragma unroll
        for (int nb = 0; nb < NF; nb++) {
            half8 bf = *(const half8*)&Bh[cur][(ncol + nb * 16 + l16) * 32 + sw];
            #pragma unroll
            for (int mb = 0; mb < 4; mb++)
                acc[mb][nb] = __builtin_amdgcn_mfma_f32_16x16x32_f16(af[mb], bf, acc[mb][nb], 0, 0, 0);
        }
        __syncthreads();                  // drains stage(cur^1); all reads of cur done
        cur ^= 1;
    }

    #pragma unroll
    for (int nb = 0; nb < NF; nb++) {
        int n = n0 + ncol + nb * 16 + l16;
        float bv = bias[n];
        int head = 0, t = 0, d = 0;
        if (MODE == 0) { head = n / 192; int rem = n % 192; t = rem / 64; d = rem % 64; }
        #pragma unroll
        for (int mb = 0; mb < 4; mb++) {
            int mbase = m0 + mrow + mb * 16 + quad * 4;
            if (MODE == 0) {
                int b = mbase >> 11;
                int s = mbase & 2047;
                long bh = b * NH + head;
                if (t == 2) {
                    half4v pack;
                    #pragma unroll
                    for (int r = 0; r < 4; r++) pack[r] = (f16)(acc[mb][nb][r] + bv);
                    *(half4v*)&Vtg[(bh * HD + d) * SEQ + s] = pack;
                } else if (t == 0) {
                    // 0.125 (1/sqrt(64)) * log2(e): QK^T lands directly in log2 domain
                    #pragma unroll
                    for (int r = 0; r < 4; r++)
                        Qh[(bh * SEQ + s + r) * HD + d] = (f16)((acc[mb][nb][r] + bv) * 0.18033688f);
                } else {
                    #pragma unroll
                    for (int r = 0; r < 4; r++)
                        Kh[(bh * SEQ + s + r) * HD + d] = (f16)(acc[mb][nb][r] + bv);
                }
            } else {
                #pragma unroll
                for (int r = 0; r < 4; r++)
                    out[(long)(mbase + r) * D_MODEL + n] = acc[mb][nb][r] + bv;
            }
        }
    }
}

// ---------------- flash attention v10: 4 qg x 2 kg split WITHIN one 64-key tile -------
// grid (16, 32), 512 threads = 8 waves. Wave (qg=wid&3, kg=wid>>2) computes 32 q-rows x
// its 32-key half of each tile. Staging identical to R9's verified pattern (one K + one
// V tile per iter, double-buffered, ONE barrier/iter). kg's key-half maps exactly to
// the existing swizzle: K rows kb in {2kg, 2kg+1}; V chunk index quad+4*kg = sw(kg).
// PV/den则 use K=32 MFMAs with pf at local k = quad*8 (same A-layout as verified qf).
// Per-wave K/V frag reads HALVED vs R9 (4+4 b128 per 32qx32k vs 8+8 per 16qx64k).
// LDS: Kl 2x8K + Vt 2x8K + Pl 8x32x36 f16 (18K) = 51200 B -> 2 blocks/CU (R10's 67.6KB
// broke the 2-block limit -> barrier-coupled 1 block/CU -> 108us).
// Cross-kg combine stride = 41 dwords (odd -> conflict-free; R7/R10's 48 was 2-bank).
__global__ __launch_bounds__(512) void attn(
    const f16* __restrict__ Qh, const f16* __restrict__ Kh, const f16* __restrict__ Vtg,
    const f16* __restrict__ E, f16* __restrict__ valh)
{
    extern __shared__ f16 sm[];
    f16* Kl0 = sm;                    // [64*64] buf0
    f16* Kl1 = sm + 4096;
    f16* Vt0 = sm + 8192;
    f16* Vt1 = sm + 12288;
    f16* Plb = sm + 16384;            // [8][32*36]
    int tid  = threadIdx.x;
    int wid  = tid >> 6;             // 0..7
    int lane = tid & 63;
    int quad = lane >> 4;
    int l16  = lane & 15;
    int qg = wid & 3;
    int kg = wid >> 2;

    int id   = blockIdx.y * 16 + blockIdx.x;   // linear dispatch id
    int xcd  = id & 7;
    int slot = id >> 3;
    int bh   = ((xcd & 3) << 3) | (slot >> 3);
    int qx   = ((xcd >> 2) << 3) | (slot & 7);
    int b  = bh >> 4;
    int h  = bh & 15;
    int qblk = qx * 128;
    int q0 = qblk + qg * 32;

    int wrow = wid * 8 + (lane >> 3);         // 0..63
    int kchunk = (lane & 7) ^ (wrow & 7);
    int sw0 = ((quad)     ^ (l16 & 7)) * 8;   // chunk quad   (keys kg=0 half for V)
    int sw1 = ((quad + 4) ^ (l16 & 7)) * 8;   // chunk quad+4 (keys kg=1 half for V)
    int swv = kg ? sw1 : sw0;

    const f16* Qbase = Qh + ((long)bh * SEQ + q0) * HD;
    half8 qf[2][2];
    #pragma unroll
    for (int m = 0; m < 2; m++)
        #pragma unroll
        for (int c = 0; c < 2; c++)
            qf[m][c] = *(const half8*)&Qbase[(long)(m * 16 + l16) * HD + c * 32 + quad * 8];

    half8 onesv;
    #pragma unroll
    for (int j = 0; j < 8; j++) onesv[j] = (f16)1.0f;

    floatx4 Of[2][4];
    floatx4 ssum[2];
    #pragma unroll
    for (int m = 0; m < 2; m++) {
        ssum[m] = (floatx4){0.f, 0.f, 0.f, 0.f};
        #pragma unroll
        for (int nb = 0; nb < 4; nb++) Of[m][nb] = (floatx4){0.f, 0.f, 0.f, 0.f};
    }

    const f16* Kb = Kh + (long)bh * SEQ * HD;
    const f16* Vb = Vtg + (long)bh * HD * SEQ;
    const f16* Eb = E + (long)qblk * SEQ;

    f16* Pl = Plb + wid * (32 * 36);

    auto stage = [&](f16* Kd, f16* Vd, int k0) {
        gload_lds16(Kb + (long)(k0 + wrow) * HD + kchunk * 8, &Kd[(wid * 8) * 64]);
        gload_lds16(Vb + (long)wrow * SEQ + k0 + kchunk * 8, &Vd[(wid * 8) * 64]);
    };

    stage(Kl0, Vt0, 0);
    __syncthreads();                  // vmcnt(0) drain: buf0 ready

    for (int t = 0; t < 32; ++t) {
        int buf = t & 1;
        f16* Kt = buf ? Kl1 : Kl0;
        f16* Vt = buf ? Vt1 : Vt0;
        int k0 = t * 64;
        if (t + 1 < 32) stage(buf ? Kl0 : Kl1, buf ? Vt0 : Vt1, k0 + 64);

        // m2 loads for this wave's key-half: issue before QK
        f16 ef[2][2][4];
        #pragma unroll
        for (int m = 0; m < 2; m++)
            #pragma unroll
            for (int r = 0; r < 4; r++) {
                const f16* Erow = Eb + (long)(qg * 32 + m * 16 + quad * 4 + r) * SEQ
                                     + k0 + kg * 32 + l16;
                #pragma unroll
                for (int kbl = 0; kbl < 2; kbl++) ef[m][kbl][r] = Erow[kbl * 16];
            }

        // QK^T: 32 q-rows x this wave's 32 keys (full d=64 per key)
        floatx4 sc[2][2];
        __builtin_amdgcn_s_setprio(1);
        #pragma unroll
        for (int kbl = 0; kbl < 2; kbl++) {
            int kb = kg * 2 + kbl;
            half8 kf0 = *(const half8*)&Kt[(kb * 16 + l16) * 64 + sw0];
            half8 kf1 = *(const half8*)&Kt[(kb * 16 + l16) * 64 + sw1];
            #pragma unroll
            for (int m = 0; m < 2; m++) {
                floatx4 sacc = (floatx4){0.f, 0.f, 0.f, 0.f};
                sacc = __builtin_amdgcn_mfma_f32_16x16x32_f16(qf[m][0], kf0, sacc, 0, 0, 0);
                sacc = __builtin_amdgcn_mfma_f32_16x16x32_f16(qf[m][1], kf1, sacc, 0, 0, 0);
                sc[m][kbl] = sacc;
            }
        }
        __builtin_amdgcn_s_setprio(0);

        // p = exp2(s + m2); Pl [32 q][36-stride], cols = local key 0..31
        #pragma unroll
        for (int m = 0; m < 2; m++)
            #pragma unroll
            for (int kbl = 0; kbl < 2; kbl++)
                #pragma unroll
                for (int r = 0; r < 4; r++) {
                    float p = EXP2(sc[m][kbl][r] + (float)ef[m][kbl][r]);
                    Pl[(m * 16 + quad * 4 + r) * 36 + kbl * 16 + l16] = (f16)p;
                }

        // wave-private round-trip: A-frag for K=32 mfma = local k quad*8..+7
        half8 pf[2];
        #pragma unroll
        for (int m = 0; m < 2; m++)
            pf[m] = *(const half8*)&Pl[(m * 16 + l16) * 36 + quad * 8];

        __builtin_amdgcn_s_setprio(1);
        #pragma unroll
        for (int m = 0; m < 2; m++)
            ssum[m] = __builtin_amdgcn_mfma_f32_16x16x32_f16(pf[m], onesv, ssum[m], 0, 0, 0);
        #pragma unroll
        for (int nb = 0; nb < 4; nb++) {
            half8 vf = *(const half8*)&Vt[(nb * 16 + l16) * 64 + swv];
            #pragma unroll
            for (int m = 0; m < 2; m++)
                Of[m][nb] = __builtin_amdgcn_mfma_f32_16x16x32_f16(pf[m], vf, Of[m][nb], 0, 0, 0);
        }
        __builtin_amdgcn_s_setprio(0);

        __syncthreads();  // drains next-tile stage; proves all reads of buf done
    }

    // ---- cross-kg combine (through LDS, reusing tile+Pl space; stride 41 dwords) ----
    float* xch = (float*)sm;
    float* p = xch + (long)(qg * 64 + lane) * 41;
    if (kg == 1) {
        #pragma unroll
        for (int m = 0; m < 2; m++)
            #pragma unroll
            for (int nb = 0; nb < 4; nb++)
                *(floatx4*)(p + (m * 4 + nb) * 4) = Of[m][nb];
        *(floatx4*)(p + 32) = ssum[0];
        *(floatx4*)(p + 36) = ssum[1];
    }
    __syncthreads();
    if (kg == 0) {
        #pragma unroll
        for (int m = 0; m < 2; m++) {
            #pragma unroll
            for (int nb = 0; nb < 4; nb++)
                Of[m][nb] += *(const floatx4*)(p + (m * 4 + nb) * 4);
            ssum[m] += *(const floatx4*)(p + 32 + m * 4);
        }
        float rinv[2][4];
        #pragma unroll
        for (int m = 0; m < 2; m++)
            #pragma unroll
            for (int r = 0; r < 4; r++) rinv[m][r] = 1.f / ssum[m][r];

        #pragma unroll
        for (int m = 0; m < 2; m++)
            #pragma unroll
            for (int nb = 0; nb < 4; nb++)
                #pragma unroll
                for (int r = 0; r < 4; r++) {
                    int q = q0 + m * 16 + quad * 4 + r;
                    int d = nb * 16 + l16;
                    valh[((long)(b * SEQ + q)) * D_MODEL + h * HD + d] = (f16)(Of[m][nb][r] * rinv[m][r]);
                }
    }
}

extern "C" void kernel_launch(void* const* d_in, const int* in_sizes, int n_in,
                              void* d_out, int out_size, void* d_ws, size_t ws_size,
                              hipStream_t stream) {
    const float* x    = (const float*)d_in[0];
    const float* mask = (const float*)d_in[1];
    const float* Wqkv = (const float*)d_in[2];
    const float* bqkv = (const float*)d_in[3];
    const float* Wout = (const float*)d_in[4];
    const float* bout = (const float*)d_in[5];
    float* out = (float*)d_out;

    char* ws = (char*)d_ws;
    f16* xh    = (f16*)(ws + 0);          // 8 MB: [4096][1024]; dead after gemm0
    f16* WqkvT = (f16*)(ws + 8388608);    // 6 MB: [3072][1024]
    f16* WoutT = (f16*)(ws + 14680064);   // 2 MB: [1024][1024]
    f16* Qh    = (f16*)(ws + 16777216);   // 8 MB: [32][2048][64] (pre-scaled 0.125*log2e)
    f16* Kh    = (f16*)(ws + 25165824);   // 8 MB: [32][2048][64]
    f16* Vtg   = (f16*)(ws + 33554432);   // 8 MB: [32][64][2048] (V transposed)
    f16* valh  = (f16*)(ws + 41943040);   // 8 MB: [4096][1024]

    bool sepE = (ws_size >= 58720256);
    f16* E = sepE ? (f16*)(ws + 50331648)   // own 8 MB buffer -> E built inside prep
                  : (f16*)(ws + 0);         // fallback: overlays xh, built after gemm0

    if (sepE) {
        prep<<<9216, 256, 0, stream>>>(x, xh, Wqkv, WqkvT, Wout, WoutT, mask, E);
        gemm_mfma<0, 128><<<dim3(24, 32), 256, 0, stream>>>(xh, WqkvT, bqkv, Qh, Kh, Vtg, nullptr, 1024);
    } else {
        prep<<<5120, 256, 0, stream>>>(x, xh, Wqkv, WqkvT, Wout, WoutT, mask, E);
        gemm_mfma<0, 128><<<dim3(24, 32), 256, 0, stream>>>(xh, WqkvT, bqkv, Qh, Kh, Vtg, nullptr, 1024);
        l2scale_cvt<<<4096, 256, 0, stream>>>(mask, E, SEQ * SEQ / 4);   // xh dead now
    }
    attn<<<dim3(16, 32), 512, 51200, stream>>>(Qh, Kh, Vtg, E, valh);
    gemm_mfma<1, 64><<<dim3(16, 32), 256, 0, stream>>>(valh, WoutT, bout, nullptr, nullptr, nullptr, out, 1024);
}

// Round 13
// 213.037 us; speedup vs baseline: 1.1863x; 1.0662x over previous
//
#include <hip/hip_runtime.h>
#include <hip/hip_bf16.h>

#define D_MODEL 1024
#define NH 16
#define HD 64
#define BATCH 2
#define SEQ 2048
#define M_TOTAL (BATCH*SEQ)   // 4096

typedef _Float16 f16;
typedef _Float16 half8 __attribute__((ext_vector_type(8)));
typedef _Float16 half4v __attribute__((ext_vector_type(4)));
typedef float floatx4 __attribute__((ext_vector_type(4)));

#if __has_builtin(__builtin_amdgcn_exp2f)
#define EXP2(x) __builtin_amdgcn_exp2f(x)
#else
#define EXP2(x) __expf(0.6931471805599453f * (x))
#endif

__device__ inline void gload_lds16(const void* g, void* l) {
    __builtin_amdgcn_global_load_lds(
        (const __attribute__((address_space(1))) unsigned int*)g,
        (__attribute__((address_space(3))) unsigned int*)l, 16, 0, 0);
}

// ---------------- fused prep: x fp32->fp16 cast + both weight transposes ----------------
__device__ void trans_body(const float* __restrict__ src, f16* __restrict__ dst,
                           int R, int C, int bx, int by) {
    __shared__ float tile[32][33];
    int tx = threadIdx.x & 31;
    int ty = threadIdx.x >> 5;        // 0..7
    int c0 = bx * 32;
    int r0 = by * 32;
    for (int yy = 0; yy < 32; yy += 8)
        tile[ty + yy][tx] = src[(long)(r0 + ty + yy) * C + c0 + tx];
    __syncthreads();
    for (int yy = 0; yy < 32; yy += 8)
        dst[(long)(c0 + ty + yy) * R + r0 + tx] = (f16)tile[tx][ty + yy];
}

__global__ __launch_bounds__(256) void prep(
    const float* __restrict__ x, f16* __restrict__ xh,
    const float* __restrict__ Wqkv, f16* __restrict__ WqkvT,
    const float* __restrict__ Wout, f16* __restrict__ WoutT)
{
    int bid = blockIdx.x;
    if (bid < 1024) {
        // x cast: 1,048,576 float4s, grid-stride x4
        int i = bid * 256 + threadIdx.x;
        #pragma unroll
        for (int it = 0; it < 4; ++it, i += 262144) {
            float4 v = ((const float4*)x)[i];
            half4v o = { (f16)v.x, (f16)v.y, (f16)v.z, (f16)v.w };
            *(half4v*)(xh + (long)i * 4) = o;
        }
    } else if (bid < 1024 + 3072) {
        int t = bid - 1024;                    // Wqkv [1024][3072] -> WqkvT
        trans_body(Wqkv, WqkvT, 1024, 3072, t % 96, t / 96);
    } else {
        int t = bid - 4096;                    // Wout [1024][1024] -> WoutT
        trans_body(Wout, WoutT, 1024, 1024, t % 32, t / 32);
    }
}

// ---------------- 128xTN-tile fp16 MFMA GEMM, BK=32 double-buffered ----------------
// Validated R10/R11 (rest-of-pipeline 141.6us vs 149.7 for BK=64 single-buffer).
// LDS 32 KB (3 blocks/CU); one barrier per K-step; next tile's DMA issued before
// compute. Rows = 32 f16 = 4 chunks of 16B; chunk p of row r holds global chunk
// p ^ (r&3); frag read chunk = quad ^ (l16&3).
// MODE 0 (TN=128): scatter -> Qh [bh][s][d] (x0.125*log2e), Kh [bh][s][d], Vtg [bh][d][s]
// MODE 1 (TN=64):  out[m][n] = acc + bias (fp32)
template<int MODE, int TN>
__global__ __launch_bounds__(256) void gemm_mfma(
    const f16* __restrict__ A, const f16* __restrict__ BT,
    const float* __restrict__ bias,
    f16* __restrict__ Qh, f16* __restrict__ Kh, f16* __restrict__ Vtg,
    float* __restrict__ out, int Kdim)
{
    constexpr int NF = TN / 32;          // n-frags per wave
    __shared__ f16 Ah[2][128 * 32];
    __shared__ f16 Bh[2][TN * 32];
    int tid  = threadIdx.x;
    int wid  = tid >> 6;
    int lane = tid & 63;
    int quad = lane >> 4;
    int l16  = lane & 15;
    int m0 = blockIdx.y * 128;
    int n0 = blockIdx.x * TN;
    int mrow = (wid >> 1) * 64;
    int ncol = (wid & 1) * (TN / 2);
    int srow = lane >> 2;                 // 0..15
    int gchunk = (lane & 3) ^ (srow & 3);
    int sw = (quad ^ (l16 & 3)) * 8;

    floatx4 acc[4][NF];
    #pragma unroll
    for (int mb = 0; mb < 4; mb++)
        #pragma unroll
        for (int nb = 0; nb < NF; nb++) acc[mb][nb] = (floatx4){0.f, 0.f, 0.f, 0.f};

    const f16* Abase = A + (long)m0 * Kdim;
    const f16* Bbase = BT + (long)n0 * Kdim;

    auto stage = [&](int buf, int k0) {
        #pragma unroll
        for (int j = 0; j < 2; j++) {
            int r = wid * 32 + j * 16 + srow;
            gload_lds16(Abase + (long)r * Kdim + k0 + gchunk * 8, &Ah[buf][(wid * 32 + j * 16) * 32]);
        }
        if (TN == 128) {
            #pragma unroll
            for (int j = 0; j < 2; j++) {
                int r = wid * 32 + j * 16 + srow;
                gload_lds16(Bbase + (long)r * Kdim + k0 + gchunk * 8, &Bh[buf][(wid * 32 + j * 16) * 32]);
            }
        } else {
            int r = wid * 16 + srow;
            gload_lds16(Bbase + (long)r * Kdim + k0 + gchunk * 8, &Bh[buf][(wid * 16) * 32]);
        }
    };

    stage(0, 0);
    __syncthreads();                      // vmcnt(0) drain: buf0 ready
    int cur = 0;
    for (int k0 = 0; k0 < Kdim; k0 += 32) {
        if (k0 + 32 < Kdim) stage(cur ^ 1, k0 + 32);   // DMA flies under compute
        half8 af[4];
        #pragma unroll
        for (int mb = 0; mb < 4; mb++)
            af[mb] = *(const half8*)&Ah[cur][(mrow + mb * 16 + l16) * 32 + sw];
        #pragma unroll
        for (int nb = 0; nb < NF; nb++) {
            half8 bf = *(const half8*)&Bh[cur][(ncol + nb * 16 + l16) * 32 + sw];
            #pragma unroll
            for (int mb = 0; mb < 4; mb++)
                acc[mb][nb] = __builtin_amdgcn_mfma_f32_16x16x32_f16(af[mb], bf, acc[mb][nb], 0, 0, 0);
        }
        __syncthreads();                  // drains stage(cur^1); all reads of cur done
        cur ^= 1;
    }

    #pragma unroll
    for (int nb = 0; nb < NF; nb++) {
        int n = n0 + ncol + nb * 16 + l16;
        float bv = bias[n];
        int head = 0, t = 0, d = 0;
        if (MODE == 0) { head = n / 192; int rem = n % 192; t = rem / 64; d = rem % 64; }
        #pragma unroll
        for (int mb = 0; mb < 4; mb++) {
            int mbase = m0 + mrow + mb * 16 + quad * 4;
            if (MODE == 0) {
                int b = mbase >> 11;
                int s = mbase & 2047;
                long bh = b * NH + head;
                if (t == 2) {
                    half4v pack;
                    #pragma unroll
                    for (int r = 0; r < 4; r++) pack[r] = (f16)(acc[mb][nb][r] + bv);
                    *(half4v*)&Vtg[(bh * HD + d) * SEQ + s] = pack;
                } else if (t == 0) {
                    // 0.125 (1/sqrt(64)) * log2(e): QK^T lands directly in log2 domain
                    #pragma unroll
                    for (int r = 0; r < 4; r++)
                        Qh[(bh * SEQ + s + r) * HD + d] = (f16)((acc[mb][nb][r] + bv) * 0.18033688f);
                } else {
                    #pragma unroll
                    for (int r = 0; r < 4; r++)
                        Kh[(bh * SEQ + s + r) * HD + d] = (f16)(acc[mb][nb][r] + bv);
                }
            } else {
                #pragma unroll
                for (int r = 0; r < 4; r++)
                    out[(long)(mbase + r) * D_MODEL + n] = acc[mb][nb][r] + bv;
            }
        }
    }
}

// ---------------- flash attention (v4 structure, twice-reproduced 66-67us) -----------
// 8 waves x 16 q-rows, K/V double-buffer + ONE barrier per k-tile, XCD-clustered
// remap, log2-domain softmax, ones-MFMA denominators.
// Change vs R9: mask read DIRECTLY as f32 (no E precompute kernel); the log2e scale
// folds into the exp2 argument as fma(m, L2E, s) — add becomes fma, zero extra VALU.
__global__ __launch_bounds__(512) void attn(
    const f16* __restrict__ Qh, const f16* __restrict__ Kh, const f16* __restrict__ Vtg,
    const float* __restrict__ mask, f16* __restrict__ valh)
{
    __shared__ f16 Kl[2][64 * 64];   // [buf][key][d], swizzled chunks
    __shared__ f16 Vt[2][64 * 64];   // [buf][d][key], swizzled chunks
    __shared__ f16 Pl[8][16 * 68];   // per-wave P [q][key], stride 68 (write-conflict-free)
    int tid  = threadIdx.x;
    int wid  = tid >> 6;             // 0..7
    int lane = tid & 63;
    int quad = lane >> 4;
    int l16  = lane & 15;

    // XCD-clustered bijective remap: each XCD sees 8 bh x 8 q-panels -> L2-resident K/V+mask
    int id   = blockIdx.y * 16 + blockIdx.x;
    int xcd  = id & 7;
    int slot = id >> 3;
    int bh   = ((xcd & 3) << 3) | (slot >> 3);
    int qx   = ((xcd >> 2) << 3) | (slot & 7);
    int b  = bh >> 4;
    int h  = bh & 15;
    int qblk = qx * 128;
    int q0 = qblk + wid * 16;

    int wrow = wid * 8 + (lane >> 3);         // 0..63
    int kchunk = (lane & 7) ^ (wrow & 7);
    int sw0 = ((quad)     ^ (l16 & 7)) * 8;   // k-half 0
    int sw1 = ((quad + 4) ^ (l16 & 7)) * 8;   // k-half 1

    const f16* Qbase = Qh + ((long)bh * SEQ + q0) * HD;
    half8 qf[2];
    #pragma unroll
    for (int c = 0; c < 2; c++)
        qf[c] = *(const half8*)&Qbase[(long)l16 * HD + c * 32 + quad * 8];

    half8 onesv;
    #pragma unroll
    for (int j = 0; j < 8; j++) onesv[j] = (f16)1.0f;

    floatx4 Of[4];
    floatx4 ssum = (floatx4){0.f, 0.f, 0.f, 0.f};
    #pragma unroll
    for (int nb = 0; nb < 4; nb++) Of[nb] = (floatx4){0.f, 0.f, 0.f, 0.f};

    const f16* Kb = Kh + (long)bh * SEQ * HD;
    const f16* Vb = Vtg + (long)bh * HD * SEQ;
    const float* Mb = mask + (long)qblk * SEQ;

    auto stage = [&](int buf, int k0) {
        gload_lds16(Kb + (long)(k0 + wrow) * HD + kchunk * 8, &Kl[buf][(wid * 8) * 64]);
        gload_lds16(Vb + (long)wrow * SEQ + k0 + kchunk * 8, &Vt[buf][(wid * 8) * 64]);
    };

    stage(0, 0);
    __syncthreads();                  // vmcnt(0) drain: buf0 ready

    const float L2E = 1.44269504f;

    auto iter = [&](const int buf, int k0) {
        bool notlast = (k0 + 64 < SEQ);
        if (notlast) stage(buf ^ 1, k0 + 64);   // DMA flies under this iter's compute

        // raw-mask loads for THIS iter: issue before QK so L2 latency hides under MFMAs
        float ef[4][4];
        #pragma unroll
        for (int r = 0; r < 4; r++) {
            const float* Mrow = Mb + (long)(wid * 16 + quad * 4 + r) * SEQ + k0 + l16;
            #pragma unroll
            for (int kb = 0; kb < 4; kb++) ef[r][kb] = Mrow[kb * 16];
        }

        // QK^T: 16 q-rows x 64 keys (result already in log2 domain)
        floatx4 sc[4];
        __builtin_amdgcn_s_setprio(1);
        #pragma unroll
        for (int kb = 0; kb < 4; kb++) {
            half8 kf0 = *(const half8*)&Kl[buf][(kb * 16 + l16) * 64 + sw0];
            half8 kf1 = *(const half8*)&Kl[buf][(kb * 16 + l16) * 64 + sw1];
            floatx4 s = (floatx4){0.f, 0.f, 0.f, 0.f};
            s = __builtin_amdgcn_mfma_f32_16x16x32_f16(qf[0], kf0, s, 0, 0, 0);
            s = __builtin_amdgcn_mfma_f32_16x16x32_f16(qf[1], kf1, s, 0, 0, 0);
            sc[kb] = s;
        }
        __builtin_amdgcn_s_setprio(0);

        // p = exp2(s + m*log2e) — the scale folds into one fma
        #pragma unroll
        for (int kb = 0; kb < 4; kb++)
            #pragma unroll
            for (int r = 0; r < 4; r++) {
                float p = EXP2(__builtin_fmaf(ef[r][kb], L2E, sc[kb][r]));
                Pl[wid][(quad * 4 + r) * 68 + kb * 16 + l16] = (f16)p;
            }

        // wave-private LDS round-trip (C-layout -> A-layout); no barrier needed
        half8 pf0 = *(const half8*)&Pl[wid][l16 * 68 + quad * 8];
        half8 pf1 = *(const half8*)&Pl[wid][l16 * 68 + 32 + quad * 8];

        __builtin_amdgcn_s_setprio(1);
        // denominators: ssum[q] += sum_key P[q][key] via ones-B MFMA
        ssum = __builtin_amdgcn_mfma_f32_16x16x32_f16(pf0, onesv, ssum, 0, 0, 0);
        ssum = __builtin_amdgcn_mfma_f32_16x16x32_f16(pf1, onesv, ssum, 0, 0, 0);
        #pragma unroll
        for (int nb = 0; nb < 4; nb++) {
            half8 vf0 = *(const half8*)&Vt[buf][(nb * 16 + l16) * 64 + sw0];
            half8 vf1 = *(const half8*)&Vt[buf][(nb * 16 + l16) * 64 + sw1];
            Of[nb] = __builtin_amdgcn_mfma_f32_16x16x32_f16(pf0, vf0, Of[nb], 0, 0, 0);
            Of[nb] = __builtin_amdgcn_mfma_f32_16x16x32_f16(pf1, vf1, Of[nb], 0, 0, 0);
        }
        __builtin_amdgcn_s_setprio(0);

        __syncthreads();  // drains stage(buf^1); proves all reads of buf done
    };

    for (int k0 = 0; k0 < SEQ; k0 += 128) {
        iter(0, k0);
        iter(1, k0 + 64);
    }

    float rinv[4];
    #pragma unroll
    for (int r = 0; r < 4; r++) rinv[r] = 1.f / ssum[r];

    #pragma unroll
    for (int nb = 0; nb < 4; nb++)
        #pragma unroll
        for (int r = 0; r < 4; r++) {
            int q = q0 + quad * 4 + r;
            int d = nb * 16 + l16;
            valh[((long)(b * SEQ + q)) * D_MODEL + h * HD + d] = (f16)(Of[nb][r] * rinv[r]);
        }
}

extern "C" void kernel_launch(void* const* d_in, const int* in_sizes, int n_in,
                              void* d_out, int out_size, void* d_ws, size_t ws_size,
                              hipStream_t stream) {
    const float* x    = (const float*)d_in[0];
    const float* mask = (const float*)d_in[1];
    const float* Wqkv = (const float*)d_in[2];
    const float* bqkv = (const float*)d_in[3];
    const float* Wout = (const float*)d_in[4];
    const float* bout = (const float*)d_in[5];
    float* out = (float*)d_out;

    char* ws = (char*)d_ws;
    f16* xh    = (f16*)(ws + 0);          // 8 MB: [4096][1024]; dead after gemm0
    f16* WqkvT = (f16*)(ws + 8388608);    // 6 MB: [3072][1024]
    f16* WoutT = (f16*)(ws + 14680064);   // 2 MB: [1024][1024]
    f16* Qh    = (f16*)(ws + 16777216);   // 8 MB: [32][2048][64] (pre-scaled 0.125*log2e)
    f16* Kh    = (f16*)(ws + 25165824);   // 8 MB: [32][2048][64]
    f16* Vtg   = (f16*)(ws + 33554432);   // 8 MB: [32][64][2048] (V transposed)
    f16* valh  = (f16*)(ws + 41943040);   // 8 MB: [4096][1024]

    prep<<<5120, 256, 0, stream>>>(x, xh, Wqkv, WqkvT, Wout, WoutT);
    gemm_mfma<0, 128><<<dim3(24, 32), 256, 0, stream>>>(xh, WqkvT, bqkv, Qh, Kh, Vtg, nullptr, 1024);
    attn<<<dim3(16, 32), 512, 0, stream>>>(Qh, Kh, Vtg, mask, valh);
    gemm_mfma<1, 64><<<dim3(16, 32), 256, 0, stream>>>(valh, WoutT, bout, nullptr, nullptr, nullptr, out, 1024);
}